// Round 8
// baseline (148.239 us; speedup 1.0000x reference)
//
#include <hip/hip_runtime.h>
#include <hip/hip_bf16.h>

// Problem constants
#define BB 4
#define SS 2048
#define DIMM 512
#define HH 8
#define DD 64
#define NQKV 1536   // 3*512

typedef float  floatx4 __attribute__((ext_vector_type(4)));
typedef short  bf16x8  __attribute__((ext_vector_type(8)));   // 8 bf16 (4 VGPRs)
typedef short  bf16x4  __attribute__((ext_vector_type(4)));   // 4 bf16 (2 VGPRs)

#define MFMA16(A, B, C) __builtin_amdgcn_mfma_f32_16x16x32_bf16(A, B, C, 0, 0, 0)

__device__ __forceinline__ unsigned short f2bf(float f) {
    unsigned int u = __float_as_uint(f);
    u += 0x7FFFu + ((u >> 16) & 1u);   // RNE
    return (unsigned short)(u >> 16);
}

// packed f32x2 -> bf16x2, single instr (RNE on gfx950); lo in bits[15:0]
__device__ __forceinline__ unsigned int cvtpk(float lo, float hi) {
    unsigned int r;
    asm("v_cvt_pk_bf16_f32 %0, %1, %2" : "=v"(r) : "v"(lo), "v"(hi));
    return r;
}

__device__ __forceinline__ float fast_exp2(float x) {
#if __has_builtin(__builtin_amdgcn_exp2f)
    return __builtin_amdgcn_exp2f(x);
#else
    return __exp2f(x);
#endif
}

// async global->LDS, 16B per lane; LDS dest = wave-uniform base + lane*16
__device__ __forceinline__ void gl_lds16(const void* g, void* l) {
    __builtin_amdgcn_global_load_lds(
        (__attribute__((address_space(1))) void*)g,
        (__attribute__((address_space(3))) void*)l,
        16, 0, 0);
}

// ---------------- prep: transpose W_qkv + W_out (x-cvt fused into qkv GEMM) ----------------
__global__ __launch_bounds__(256) void k_prep(
    const float* __restrict__ W_qkv, const float* __restrict__ W_out,
    unsigned short* __restrict__ Wq_t, unsigned short* __restrict__ Wo_t) {
    __shared__ float t[32][33];
    int bid = blockIdx.x, tid = threadIdx.x;
    const float* in; unsigned short* out; int R = 512, C, bx, by;
    if (bid < 768) { in = W_qkv; out = Wq_t; C = 1536; bx = bid % 48; by = bid / 48; }
    else           { in = W_out; out = Wo_t; C = 512;  int blk = bid - 768; bx = blk % 16; by = blk / 16; }
    int tx = tid & 31, ty = tid >> 5;       // 32 x 8
    int c0 = bx * 32, r0 = by * 32;
    for (int i = 0; i < 4; i++) {
        int r = r0 + ty + i * 8;
        t[ty + i * 8][tx] = in[(size_t)r * C + c0 + tx];
    }
    __syncthreads();
    for (int i = 0; i < 4; i++) {
        int cc = c0 + ty + i * 8;
        out[(size_t)cc * R + r0 + tx] = f2bf(t[tx][ty + i * 8]);
    }
}

// ---------------- fused QKV GEMM: C[8192,1536] = cvt(x)[8192,512] @ Wq_t^T ----------------
__global__ __launch_bounds__(256, 3) void k_gemm_qkv(
    const float* __restrict__ X,             // [8192][512] f32
    const unsigned short* __restrict__ Bt,   // [1536][512] bf16 (n-major)
    const float* __restrict__ log_temp,
    unsigned short* __restrict__ Qb,
    unsigned short* __restrict__ Kb,
    unsigned short* __restrict__ Vt) {
    __shared__ __align__(16) unsigned short smem[3 * 8192];   // As | Bs0 | Bs1 (48 KB)
    unsigned short* As = smem;
    const int K = 512;
    int m0 = blockIdx.x * 128, n0 = blockIdx.y * 128;
    int tid = threadIdx.x;
    int w = tid >> 6, lane = tid & 63;
    int c = lane & 15, q4 = lane >> 4;
    int wm = w >> 1, wn = w & 1;
    float qscale = __expf(log_temp[0]) * 1.44269504f;  // temp * log2(e), folded into Q

    int arow[4], agcc[4];
    for (int j = 0; j < 4; j++) {
        int cidx = w * 256 + j * 64 + lane;
        arow[j] = cidx >> 3;
        agcc[j] = (cidx & 7) ^ (arow[j] & 7);
    }
    floatx4 a0[4], a1[4];                    // staged raw f32 (32 VGPR)

    auto load_A = [&](int k0) {
        for (int j = 0; j < 4; j++) {
            const float* p = X + (size_t)(m0 + arow[j]) * K + k0 + agcc[j] * 8;
            a0[j] = *(const floatx4*)p;
            a1[j] = *(const floatx4*)(p + 4);
        }
    };
    auto issue_B = [&](int k0, int bsel) {
        unsigned short* Bdst = smem + 8192 + bsel * 8192;
        for (int i = 0; i < 4; i++) {
            int cidx = w * 256 + i * 64 + lane;
            int row = cidx >> 3, cc = cidx & 7;
            int gcc = cc ^ (row & 7);
            gl_lds16(Bt + (size_t)(n0 + row) * K + k0 + gcc * 8,
                     Bdst + (size_t)(w * 256 + i * 64) * 8);
        }
    };

    floatx4 acc[4][4] = {};
    load_A(0);
    issue_B(0, 0);
    int bsel = 0;

    for (int k0 = 0; k0 < K; k0 += 64) {
        __syncthreads();                     // drains B(k0)+A-regs(k0)
        for (int j = 0; j < 4; j++) {        // cvt + lane-linear ds_write (conflict-free)
            union { bf16x8 v; unsigned int u[4]; } t;
            t.u[0] = cvtpk(a0[j][0], a0[j][1]);
            t.u[1] = cvtpk(a0[j][2], a0[j][3]);
            t.u[2] = cvtpk(a1[j][0], a1[j][1]);
            t.u[3] = cvtpk(a1[j][2], a1[j][3]);
            *(bf16x8*)&As[(size_t)(w * 256 + j * 64 + lane) * 8] = t.v;
        }
        __syncthreads();                     // As visible
        if (k0 + 64 < K) { issue_B(k0 + 64, bsel ^ 1); load_A(k0 + 64); }

        const unsigned short* Bcur = smem + 8192 + bsel * 8192;
        for (int kh = 0; kh < 2; kh++) {
            bf16x8 aF[4], bF[4];
            for (int mt = 0; mt < 4; mt++) {
                int row = wm * 64 + mt * 16 + c;
                aF[mt] = *(const bf16x8*)&As[row * 64 + (((kh * 4 + q4) ^ (row & 7)) * 8)];
            }
            for (int nt = 0; nt < 4; nt++) {
                int row = wn * 64 + nt * 16 + c;
                bF[nt] = *(const bf16x8*)&Bcur[row * 64 + (((kh * 4 + q4) ^ (row & 7)) * 8)];
            }
            for (int mt = 0; mt < 4; mt++)
                for (int nt = 0; nt < 4; nt++)
                    acc[mt][nt] = MFMA16(aF[mt], bF[nt], acc[mt][nt]);
        }
        bsel ^= 1;
    }

    // epilogue: C/D layout col=lane&15, row=(lane>>4)*4+reg
    if (n0 < 1024) {
        for (int nt = 0; nt < 4; nt++) {
            int n = n0 + wn * 64 + nt * 16 + c;
            int t = n >> 9, inner = n & 511;
            int h = inner >> 6, d = inner & 63;
            for (int mt = 0; mt < 4; mt++) {
                for (int r = 0; r < 4; r++) {
                    int m = m0 + wm * 64 + mt * 16 + q4 * 4 + r;
                    int b = m >> 11, s = m & 2047;
                    int bh = b * 8 + h;
                    float v = acc[mt][nt][r];
                    if (t == 0)  Qb[((size_t)bh * SS + s) * 64 + d] = f2bf(v * qscale);
                    else         Kb[((size_t)bh * SS + s) * 64 + d] = f2bf(v);
                }
            }
        }
    } else {
        // V: transpose C-tile through LDS, store coalesced to Vt [bh][64][s]
        unsigned short* T = smem;   // [64 n][128 m], stride 136
        int b = m0 >> 11, s_base = m0 & 2047;
        for (int half = 0; half < 2; half++) {
            __syncthreads();
            if (wn == half) {
                for (int nt = 0; nt < 4; nt++)
                    for (int mt = 0; mt < 4; mt++)
                        for (int r = 0; r < 4; r++)
                            T[(nt * 16 + c) * 136 + wm * 64 + mt * 16 + q4 * 4 + r] =
                                f2bf(acc[mt][nt][r]);
            }
            __syncthreads();
            for (int rr = 0; rr < 4; rr++) {
                int nl = w * 16 + rr * 4 + q4;        // 0..63
                int ml = c * 8;                        // 0..120
                bf16x8 v = *(const bf16x8*)&T[nl * 136 + ml];
                int n = n0 + half * 64 + nl;           // 1024..1535
                int h = (n >> 6) - 16, d = n & 63;
                int bh = b * 8 + h;
                *(bf16x8*)(Vt + ((size_t)bh * 64 + d) * SS + s_base + ml) = v;
            }
        }
    }
}

// ---------------- flash attention: S^T form, 8 waves, split-j, MIXED window order ----------------
// R7's register-held stagger FAILED correctness -> reverted. R8 retests the
// phase-locking theory with ZERO held state: wg0 uses the R5/R6-proven MFMA-front
// order (QKT g0; QKT g1; mask; EPV g0; EPV g1), wg1 uses the R2/R3-proven
// interleaved order (per g: QKT; mask; EPV). Both are valid serializations of the
// SAME tile's work; no register lifetime crosses a barrier; no VGPR growth. The
// two orders make the groups demand MFMA vs VALU at different times mid-window
// (m114: cross-wave MFMA||VALU overlap is free when waves are at different phases).
__global__ __launch_bounds__(512, 4) void k_attn(
    const unsigned short* __restrict__ Qb,   // [BH][S][64], pre-scaled by temp*log2e
    const unsigned short* __restrict__ Kb,   // [BH][S][64]
    const unsigned short* __restrict__ Vt,   // [BH][64][S]
    unsigned short* __restrict__ AO) {       // [B][S][512]
    __shared__ unsigned short KVs[2][2][2][64 * 64];  // [kv][wg][buf][j*64+d], 64 KB
    int bid = blockIdx.x;
    int swz = (bid & 7) * 64 + (bid >> 3);   // 512 = 8 * 64, bijective
    int q0 = (swz & 15) * 128;
    int bh = swz >> 4;                        // 0..31; XCD k gets bh 4k..4k+3
    int h = bh & 7, b = bh >> 3;
    int tid = threadIdx.x, w = tid >> 6, lane = tid & 63;
    int wg = w >> 2, wi = w & 3;
    int c = lane & 15, q4 = lane >> 4;

    const unsigned short* Kbase = Kb + (size_t)bh * SS * 64 + (size_t)wg * 1024 * 64;
    const unsigned short* Vbase = Vt + (size_t)bh * 64 * SS;  // + wg*1024 in s below

    // Q B-frags for two m-tiles (K=32 layout: col m = lane&15, k = q4*8+i)
    bf16x8 qf[2][2];
    for (int mt = 0; mt < 2; mt++) {
        const unsigned short* qp = Qb + ((size_t)bh * SS + q0 + wi * 32 + mt * 16 + c) * 64;
        qf[mt][0] = *(const bf16x8*)(qp + q4 * 8);
        qf[mt][1] = *(const bf16x8*)(qp + 32 + q4 * 8);
    }
    bf16x8 ones;
    for (int i = 0; i < 8; i++) ones[i] = (short)0x3F80;   // bf16 1.0
    const floatx4 fzero = {};                 // shared zero C-operand

    // staging: per group, 4 waves x 2 issues cover 512 K-chunks + 512 V-chunks (16B)
    int cidx0 = wi * 128 + lane, cidx1 = cidx0 + 64;
    int row0 = cidx0 >> 3, cc0 = cidx0 & 7;
    int row1 = cidx1 >> 3, cc1 = cidx1 & 7;
    int fk0 = (row0 & 3) | ((row0 >> 1) & 4);
    int fk1 = (row1 & 3) | ((row1 >> 1) & 4);
    const unsigned short* ksrc0 = Kbase + (size_t)row0 * 64 + (cc0 ^ fk0) * 8;
    const unsigned short* ksrc1 = Kbase + (size_t)row1 * 64 + (cc1 ^ fk1) * 8;
    const unsigned short* vsrc0 = Vbase + (size_t)row0 * SS + wg * 1024 + (cc0 ^ (row0 & 7)) * 8;
    const unsigned short* vsrc1 = Vbase + (size_t)row1 * SS + wg * 1024 + (cc1 ^ (row1 & 7)) * 8;
    unsigned short* kdst0 = &KVs[0][wg][0][0] + wi * 1024;
    unsigned short* kdst1 = kdst0 + 512;
    unsigned short* vdst0 = &KVs[1][wg][0][0] + wi * 1024;
    unsigned short* vdst1 = vdst0 + 512;

    // prime buffer 0 (this group's first tile)
    gl_lds16(ksrc0, kdst0); gl_lds16(ksrc1, kdst1);
    gl_lds16(vsrc0, vdst0); gl_lds16(vsrc1, vdst1);

    int mask_j0 = (q0 + wi * 32) & ~63;      // absolute diag tile for these rows
    int mglob0 = q0 + wi * 32 + c;           // diag column for m-tile 0
    int mglob1 = mglob0 + 16;                // diag column for m-tile 1
    floatx4 oacc[2][4] = {};
    floatx4 osum[2] = {};                     // row sums via ones-column MFMA

    for (int jt = 0; jt < 16; jt++) {
        int buf = jt & 1;
        int j0 = wg * 1024 + jt * 64;        // absolute j of this tile
        __syncthreads();                     // drains last iter's prefetch
        if (jt + 1 < 16) {
            int jl = (jt + 1) * 64;          // group-local j offset
            gl_lds16(ksrc0 + (size_t)jl * 64, kdst0 + (buf ^ 1) * 4096);
            gl_lds16(ksrc1 + (size_t)jl * 64, kdst1 + (buf ^ 1) * 4096);
            gl_lds16(vsrc0 + jl, vdst0 + (buf ^ 1) * 4096);
            gl_lds16(vsrc1 + jl, vdst1 + (buf ^ 1) * 4096);
        }
        const unsigned short* Ksb = &KVs[0][wg][buf][0];
        const unsigned short* Vsb = &KVs[1][wg][buf][0];

        if (wg == 0) {
            // ---- MFMA-front order (proven R5/R6): both QKTs, mask, both EPVs ----
            floatx4 sa[2][2][2];              // [g][mt][inner]
            for (int g = 0; g < 2; g++) {
                bf16x8 kf[2][2];
                for (int inner = 0; inner < 2; inner++) {
                    int row = g * 32 + ((c >> 2) << 3) + inner * 4 + (c & 3);
                    kf[inner][0] = *(const bf16x8*)&Ksb[row * 64 + ((q4 ^ (c & 7)) * 8)];
                    kf[inner][1] = *(const bf16x8*)&Ksb[row * 64 + (((4 + q4) ^ (c & 7)) * 8)];
                }
                __builtin_amdgcn_s_setprio(1);
                for (int mt = 0; mt < 2; mt++)
                    for (int inner = 0; inner < 2; inner++) {
                        floatx4 t = MFMA16(kf[inner][0], qf[mt][0], fzero);
                        t = MFMA16(kf[inner][1], qf[mt][1], t);
                        sa[g][mt][inner] = t;
                    }
                __builtin_amdgcn_s_setprio(0);
            }
            if (j0 == mask_j0) {              // wave-uniform, 1/16 iterations
                for (int g = 0; g < 2; g++)
                    for (int inner = 0; inner < 2; inner++)
                        for (int r = 0; r < 4; r++) {
                            int jg = j0 + g * 32 + q4 * 8 + inner * 4 + r;
                            if (jg == mglob0) sa[g][0][inner][r] = -1e30f;
                            if (jg == mglob1) sa[g][1][inner][r] = -1e30f;
                        }
            }
            for (int g = 0; g < 2; g++) {
                bf16x8 vf[4];
                for (int dt = 0; dt < 4; dt++) {
                    int vrow = dt * 16 + c;
                    vf[dt] = *(const bf16x8*)&Vsb[vrow * 64 + (((g * 4 + q4) ^ (c & 7)) * 8)];
                }
                for (int mt = 0; mt < 2; mt++) {
                    float e0 = fast_exp2(sa[g][mt][0][0]), e1 = fast_exp2(sa[g][mt][0][1]);
                    float e2 = fast_exp2(sa[g][mt][0][2]), e3 = fast_exp2(sa[g][mt][0][3]);
                    float e4 = fast_exp2(sa[g][mt][1][0]), e5 = fast_exp2(sa[g][mt][1][1]);
                    float e6 = fast_exp2(sa[g][mt][1][2]), e7 = fast_exp2(sa[g][mt][1][3]);
                    union { bf16x8 v; unsigned int u[4]; } P;
                    P.u[0] = cvtpk(e0, e1); P.u[1] = cvtpk(e2, e3);
                    P.u[2] = cvtpk(e4, e5); P.u[3] = cvtpk(e6, e7);
                    __builtin_amdgcn_s_setprio(1);
                    for (int dt = 0; dt < 4; dt++)
                        oacc[mt][dt] = MFMA16(P.v, vf[dt], oacc[mt][dt]);
                    osum[mt] = MFMA16(P.v, ones, osum[mt]);
                    __builtin_amdgcn_s_setprio(0);
                }
            }
        } else {
            // ---- interleaved order (proven R2/R3): per g: QKT, mask, EPV ----
            for (int g = 0; g < 2; g++) {
                bf16x8 kf[2][2];
                for (int inner = 0; inner < 2; inner++) {
                    int row = g * 32 + ((c >> 2) << 3) + inner * 4 + (c & 3);
                    kf[inner][0] = *(const bf16x8*)&Ksb[row * 64 + ((q4 ^ (c & 7)) * 8)];
                    kf[inner][1] = *(const bf16x8*)&Ksb[row * 64 + (((4 + q4) ^ (c & 7)) * 8)];
                }
                bf16x8 vf[4];
                for (int dt = 0; dt < 4; dt++) {
                    int vrow = dt * 16 + c;
                    vf[dt] = *(const bf16x8*)&Vsb[vrow * 64 + (((g * 4 + q4) ^ (c & 7)) * 8)];
                }
                floatx4 sg[2][2];             // [mt][inner]
                __builtin_amdgcn_s_setprio(1);
                for (int mt = 0; mt < 2; mt++)
                    for (int inner = 0; inner < 2; inner++) {
                        floatx4 t = MFMA16(kf[inner][0], qf[mt][0], fzero);
                        t = MFMA16(kf[inner][1], qf[mt][1], t);
                        sg[mt][inner] = t;
                    }
                __builtin_amdgcn_s_setprio(0);
                if (j0 == mask_j0) {          // wave-uniform, rare
                    for (int inner = 0; inner < 2; inner++)
                        for (int r = 0; r < 4; r++) {
                            int jg = j0 + g * 32 + q4 * 8 + inner * 4 + r;
                            if (jg == mglob0) sg[0][inner][r] = -1e30f;
                            if (jg == mglob1) sg[1][inner][r] = -1e30f;
                        }
                }
                for (int mt = 0; mt < 2; mt++) {
                    float e0 = fast_exp2(sg[mt][0][0]), e1 = fast_exp2(sg[mt][0][1]);
                    float e2 = fast_exp2(sg[mt][0][2]), e3 = fast_exp2(sg[mt][0][3]);
                    float e4 = fast_exp2(sg[mt][1][0]), e5 = fast_exp2(sg[mt][1][1]);
                    float e6 = fast_exp2(sg[mt][1][2]), e7 = fast_exp2(sg[mt][1][3]);
                    union { bf16x8 v; unsigned int u[4]; } P;
                    P.u[0] = cvtpk(e0, e1); P.u[1] = cvtpk(e2, e3);
                    P.u[2] = cvtpk(e4, e5); P.u[3] = cvtpk(e6, e7);
                    __builtin_amdgcn_s_setprio(1);
                    for (int dt = 0; dt < 4; dt++)
                        oacc[mt][dt] = MFMA16(P.v, vf[dt], oacc[mt][dt]);
                    osum[mt] = MFMA16(P.v, ones, osum[mt]);
                    __builtin_amdgcn_s_setprio(0);
                }
            }
        }
    }

    // ---- merge the two j-halves (exact: plain sums), then group 0 stores ----
    __syncthreads();                          // all compute done; LDS reusable
    float* p = (float*)&KVs[0][0][0][0] + ((size_t)(wi * 64 + lane)) * 41;
    if (wg == 1) {
        for (int mt = 0; mt < 2; mt++)
            for (int dt = 0; dt < 4; dt++)
                for (int r = 0; r < 4; r++)
                    p[mt * 16 + dt * 4 + r] = oacc[mt][dt][r];
        for (int mt = 0; mt < 2; mt++)
            for (int r = 0; r < 4; r++)
                p[32 + mt * 4 + r] = osum[mt][r];
    }
    __syncthreads();
    if (wg == 0) {
        for (int mt = 0; mt < 2; mt++)
            for (int dt = 0; dt < 4; dt++)
                for (int r = 0; r < 4; r++)
                    oacc[mt][dt][r] += p[mt * 16 + dt * 4 + r];
        for (int mt = 0; mt < 2; mt++)
            for (int r = 0; r < 4; r++)
                osum[mt][r] += p[32 + mt * 4 + r];

        for (int mt = 0; mt < 2; mt++) {
            for (int r = 0; r < 4; r++) {
                float inv = 1.0f / osum[mt][r];
                int s = q0 + wi * 32 + mt * 16 + q4 * 4 + r;
                for (int dt = 0; dt < 4; dt++)
                    AO[((size_t)b * SS + s) * 512 + h * 64 + dt * 16 + c] =
                        f2bf(oacc[mt][dt][r] * inv);
            }
        }
    }
}

// ---------------- output GEMM: out[8192,512] = AO @ Wo_t^T + bias (fp32 out) ----------------
__global__ __launch_bounds__(256, 4) void k_gemm_out(
    const unsigned short* __restrict__ A,    // [8192][512] bf16
    const unsigned short* __restrict__ Bt,   // [512][512] bf16 (n-major)
    const float* __restrict__ bias,
    float* __restrict__ out) {
    __shared__ unsigned short As[64 * 64];    // 8 KB
    __shared__ unsigned short Bs[64 * 64];    // 8 KB
    const int K = 512;
    int m0 = blockIdx.x * 64, n0 = blockIdx.y * 64;
    int tid = threadIdx.x;
    int w = tid >> 6, lane = tid & 63;
    int c = lane & 15, q4 = lane >> 4;

    floatx4 acc[4] = {};

    for (int k0 = 0; k0 < K; k0 += 64) {
        __syncthreads();
        for (int i = 0; i < 2; i++) {
            int cidx = i * 256 + tid;             // 0..511 chunks (each of As, Bs)
            int row = cidx >> 3, cc = cidx & 7;
            int gcc = cc ^ (row & 7);
            gl_lds16(A + (size_t)(m0 + row) * K + k0 + gcc * 8,
                     As + (size_t)(i * 256 + w * 64) * 8);
            gl_lds16(Bt + (size_t)(n0 + row) * K + k0 + gcc * 8,
                     Bs + (size_t)(i * 256 + w * 64) * 8);
        }
        __syncthreads();
        for (int kh = 0; kh < 2; kh++) {
            int row = w * 16 + c;
            bf16x8 aF = *(const bf16x8*)&As[row * 64 + (((kh * 4 + q4) ^ (row & 7)) * 8)];
            bf16x8 bF[4];
            for (int nt = 0; nt < 4; nt++) {
                int rown = nt * 16 + c;
                bF[nt] = *(const bf16x8*)&Bs[rown * 64 + (((kh * 4 + q4) ^ (rown & 7)) * 8)];
            }
            for (int nt = 0; nt < 4; nt++)
                acc[nt] = MFMA16(aF, bF[nt], acc[nt]);
        }
    }

    for (int nt = 0; nt < 4; nt++) {
        int n = n0 + nt * 16 + c;
        float bv = bias[n];
        for (int r = 0; r < 4; r++) {
            int m = m0 + w * 16 + q4 * 4 + r;
            out[(size_t)m * 512 + n] = acc[nt][r] + bv;
        }
    }
}

extern "C" void kernel_launch(void* const* d_in, const int* in_sizes, int n_in,
                              void* d_out, int out_size, void* d_ws, size_t ws_size,
                              hipStream_t stream) {
    const float* x        = (const float*)d_in[0];
    const float* W_qkv    = (const float*)d_in[1];
    const float* log_temp = (const float*)d_in[2];
    const float* W_out    = (const float*)d_in[3];
    const float* b_out    = (const float*)d_in[4];
    float* out = (float*)d_out;

    char* ws = (char*)d_ws;
    unsigned short* Wq_t = (unsigned short*)(ws + 8388608);    //  1.5MB [1536][512]
    unsigned short* Wo_t = (unsigned short*)(ws + 9961472);    //  0.5MB [512][512]
    unsigned short* Qb   = (unsigned short*)(ws + 10485760);   //  8 MB  [32][2048][64]
    unsigned short* Kb   = (unsigned short*)(ws + 18874368);   //  8 MB  [32][2048][64]
    unsigned short* Vt   = (unsigned short*)(ws + 27262976);   //  8 MB  [32][64][2048]
    unsigned short* AO   = (unsigned short*)(ws + 35651584);   //  8 MB  [8192][512]

    k_prep<<<1024, 256, 0, stream>>>(W_qkv, W_out, Wq_t, Wo_t);
    k_gemm_qkv<<<dim3(64, 12), 256, 0, stream>>>(x, Wq_t, log_temp, Qb, Kb, Vt);
    k_attn<<<512, 512, 0, stream>>>(Qb, Kb, Vt, AO);
    k_gemm_out<<<dim3(128, 8), 256, 0, stream>>>(AO, Wo_t, b_out, out);
}

// Round 10
// 138.466 us; speedup vs baseline: 1.0706x; 1.0706x over previous
//
#include <hip/hip_runtime.h>
#include <hip/hip_bf16.h>

// Problem constants
#define BB 4
#define SS 2048
#define DIMM 512
#define HH 8
#define DD 64
#define NQKV 1536   // 3*512

typedef float  floatx4 __attribute__((ext_vector_type(4)));
typedef short  bf16x8  __attribute__((ext_vector_type(8)));   // 8 bf16 (4 VGPRs)
typedef short  bf16x4  __attribute__((ext_vector_type(4)));   // 4 bf16 (2 VGPRs)

#define MFMA16(A, B, C) __builtin_amdgcn_mfma_f32_16x16x32_bf16(A, B, C, 0, 0, 0)

__device__ __forceinline__ unsigned short f2bf(float f) {
    unsigned int u = __float_as_uint(f);
    u += 0x7FFFu + ((u >> 16) & 1u);   // RNE
    return (unsigned short)(u >> 16);
}

// packed f32x2 -> bf16x2, single instr (RNE on gfx950); lo in bits[15:0]
__device__ __forceinline__ unsigned int cvtpk(float lo, float hi) {
    unsigned int r;
    asm("v_cvt_pk_bf16_f32 %0, %1, %2" : "=v"(r) : "v"(lo), "v"(hi));
    return r;
}

__device__ __forceinline__ float fast_exp2(float x) {
#if __has_builtin(__builtin_amdgcn_exp2f)
    return __builtin_amdgcn_exp2f(x);
#else
    return __exp2f(x);
#endif
}

// async global->LDS, 16B per lane; LDS dest = wave-uniform base + lane*16
__device__ __forceinline__ void gl_lds16(const void* g, void* l) {
    __builtin_amdgcn_global_load_lds(
        (__attribute__((address_space(1))) void*)g,
        (__attribute__((address_space(3))) void*)l,
        16, 0, 0);
}

// ---------------- prep: transpose W_qkv + W_out (x-cvt fused into qkv GEMM) ----------------
__global__ __launch_bounds__(256) void k_prep(
    const float* __restrict__ W_qkv, const float* __restrict__ W_out,
    unsigned short* __restrict__ Wq_t, unsigned short* __restrict__ Wo_t) {
    __shared__ float t[32][33];
    int bid = blockIdx.x, tid = threadIdx.x;
    const float* in; unsigned short* out; int R = 512, C, bx, by;
    if (bid < 768) { in = W_qkv; out = Wq_t; C = 1536; bx = bid % 48; by = bid / 48; }
    else           { in = W_out; out = Wo_t; C = 512;  int blk = bid - 768; bx = blk % 16; by = blk / 16; }
    int tx = tid & 31, ty = tid >> 5;       // 32 x 8
    int c0 = bx * 32, r0 = by * 32;
    for (int i = 0; i < 4; i++) {
        int r = r0 + ty + i * 8;
        t[ty + i * 8][tx] = in[(size_t)r * C + c0 + tx];
    }
    __syncthreads();
    for (int i = 0; i < 4; i++) {
        int cc = c0 + ty + i * 8;
        out[(size_t)cc * R + r0 + tx] = f2bf(t[tx][ty + i * 8]);
    }
}

// ---------------- fused QKV GEMM: C[8192,1536] = cvt(x)[8192,512] @ Wq_t^T ----------------
__global__ __launch_bounds__(256, 3) void k_gemm_qkv(
    const float* __restrict__ X,             // [8192][512] f32
    const unsigned short* __restrict__ Bt,   // [1536][512] bf16 (n-major)
    const float* __restrict__ log_temp,
    unsigned short* __restrict__ Qb,
    unsigned short* __restrict__ Kb,
    unsigned short* __restrict__ Vt) {
    __shared__ __align__(16) unsigned short smem[3 * 8192];   // As | Bs0 | Bs1 (48 KB)
    unsigned short* As = smem;
    const int K = 512;
    int m0 = blockIdx.x * 128, n0 = blockIdx.y * 128;
    int tid = threadIdx.x;
    int w = tid >> 6, lane = tid & 63;
    int c = lane & 15, q4 = lane >> 4;
    int wm = w >> 1, wn = w & 1;
    float qscale = __expf(log_temp[0]) * 1.44269504f;  // temp * log2(e), folded into Q

    int arow[4], agcc[4];
    for (int j = 0; j < 4; j++) {
        int cidx = w * 256 + j * 64 + lane;
        arow[j] = cidx >> 3;
        agcc[j] = (cidx & 7) ^ (arow[j] & 7);
    }
    floatx4 a0[4], a1[4];                    // staged raw f32 (32 VGPR)

    auto load_A = [&](int k0) {
        for (int j = 0; j < 4; j++) {
            const float* p = X + (size_t)(m0 + arow[j]) * K + k0 + agcc[j] * 8;
            a0[j] = *(const floatx4*)p;
            a1[j] = *(const floatx4*)(p + 4);
        }
    };
    auto issue_B = [&](int k0, int bsel) {
        unsigned short* Bdst = smem + 8192 + bsel * 8192;
        for (int i = 0; i < 4; i++) {
            int cidx = w * 256 + i * 64 + lane;
            int row = cidx >> 3, cc = cidx & 7;
            int gcc = cc ^ (row & 7);
            gl_lds16(Bt + (size_t)(n0 + row) * K + k0 + gcc * 8,
                     Bdst + (size_t)(w * 256 + i * 64) * 8);
        }
    };

    floatx4 acc[4][4] = {};
    load_A(0);
    issue_B(0, 0);
    int bsel = 0;

    for (int k0 = 0; k0 < K; k0 += 64) {
        __syncthreads();                     // drains B(k0)+A-regs(k0)
        for (int j = 0; j < 4; j++) {        // cvt + lane-linear ds_write (conflict-free)
            union { bf16x8 v; unsigned int u[4]; } t;
            t.u[0] = cvtpk(a0[j][0], a0[j][1]);
            t.u[1] = cvtpk(a0[j][2], a0[j][3]);
            t.u[2] = cvtpk(a1[j][0], a1[j][1]);
            t.u[3] = cvtpk(a1[j][2], a1[j][3]);
            *(bf16x8*)&As[(size_t)(w * 256 + j * 64 + lane) * 8] = t.v;
        }
        __syncthreads();                     // As visible
        if (k0 + 64 < K) { issue_B(k0 + 64, bsel ^ 1); load_A(k0 + 64); }

        const unsigned short* Bcur = smem + 8192 + bsel * 8192;
        for (int kh = 0; kh < 2; kh++) {
            bf16x8 aF[4], bF[4];
            for (int mt = 0; mt < 4; mt++) {
                int row = wm * 64 + mt * 16 + c;
                aF[mt] = *(const bf16x8*)&As[row * 64 + (((kh * 4 + q4) ^ (row & 7)) * 8)];
            }
            for (int nt = 0; nt < 4; nt++) {
                int row = wn * 64 + nt * 16 + c;
                bF[nt] = *(const bf16x8*)&Bcur[row * 64 + (((kh * 4 + q4) ^ (row & 7)) * 8)];
            }
            for (int mt = 0; mt < 4; mt++)
                for (int nt = 0; nt < 4; nt++)
                    acc[mt][nt] = MFMA16(aF[mt], bF[nt], acc[mt][nt]);
        }
        bsel ^= 1;
    }

    // epilogue: C/D layout col=lane&15, row=(lane>>4)*4+reg
    if (n0 < 1024) {
        for (int nt = 0; nt < 4; nt++) {
            int n = n0 + wn * 64 + nt * 16 + c;
            int t = n >> 9, inner = n & 511;
            int h = inner >> 6, d = inner & 63;
            for (int mt = 0; mt < 4; mt++) {
                for (int r = 0; r < 4; r++) {
                    int m = m0 + wm * 64 + mt * 16 + q4 * 4 + r;
                    int b = m >> 11, s = m & 2047;
                    int bh = b * 8 + h;
                    float v = acc[mt][nt][r];
                    if (t == 0)  Qb[((size_t)bh * SS + s) * 64 + d] = f2bf(v * qscale);
                    else         Kb[((size_t)bh * SS + s) * 64 + d] = f2bf(v);
                }
            }
        }
    } else {
        // V: transpose C-tile through LDS, store coalesced to Vt [bh][64][s]
        unsigned short* T = smem;   // [64 n][128 m], stride 136
        int b = m0 >> 11, s_base = m0 & 2047;
        for (int half = 0; half < 2; half++) {
            __syncthreads();
            if (wn == half) {
                for (int nt = 0; nt < 4; nt++)
                    for (int mt = 0; mt < 4; mt++)
                        for (int r = 0; r < 4; r++)
                            T[(nt * 16 + c) * 136 + wm * 64 + mt * 16 + q4 * 4 + r] =
                                f2bf(acc[mt][nt][r]);
            }
            __syncthreads();
            for (int rr = 0; rr < 4; rr++) {
                int nl = w * 16 + rr * 4 + q4;        // 0..63
                int ml = c * 8;                        // 0..120
                bf16x8 v = *(const bf16x8*)&T[nl * 136 + ml];
                int n = n0 + half * 64 + nl;           // 1024..1535
                int h = (n >> 6) - 16, d = n & 63;
                int bh = b * 8 + h;
                *(bf16x8*)(Vt + ((size_t)bh * 64 + d) * SS + s_base + ml) = v;
            }
        }
    }
}

// ---------------- flash attention: S^T form, 8 waves, split-j (R6 state, best verified) ----------------
// 1D grid 512, XCD-swizzled (K/V L2-resident: FETCH 70->12MB, verified R3).
// Order within a tile: QKT(g0); QKT(g1); mask; EPV(g0); EPV(g1) -- sa held across the
// mask branch so exp2 trails its producer by a full MFMA burst (verified R5/R6).
// R4/R7/R8 post-mortems: deeper pipelining (2-deep regs, cross-tile held state, mixed
// window order) all failed or were neutral -- this schedule is the verified optimum.
// Row sums free via ones-column MFMA; K rows permuted (sigma) so S^T acc == K=32
// A-frag layout; P packed with v_cvt_pk_bf16_f32.
__global__ __launch_bounds__(512, 4) void k_attn(
    const unsigned short* __restrict__ Qb,   // [BH][S][64], pre-scaled by temp*log2e
    const unsigned short* __restrict__ Kb,   // [BH][S][64]
    const unsigned short* __restrict__ Vt,   // [BH][64][S]
    unsigned short* __restrict__ AO) {       // [B][S][512]
    __shared__ unsigned short KVs[2][2][2][64 * 64];  // [kv][wg][buf][j*64+d], 64 KB
    int bid = blockIdx.x;
    int swz = (bid & 7) * 64 + (bid >> 3);   // 512 = 8 * 64, bijective
    int q0 = (swz & 15) * 128;
    int bh = swz >> 4;                        // 0..31; XCD k gets bh 4k..4k+3
    int h = bh & 7, b = bh >> 3;
    int tid = threadIdx.x, w = tid >> 6, lane = tid & 63;
    int wg = w >> 2, wi = w & 3;
    int c = lane & 15, q4 = lane >> 4;

    const unsigned short* Kbase = Kb + (size_t)bh * SS * 64 + (size_t)wg * 1024 * 64;
    const unsigned short* Vbase = Vt + (size_t)bh * 64 * SS;  // + wg*1024 in s below

    // Q B-frags for two m-tiles (K=32 layout: col m = lane&15, k = q4*8+i)
    bf16x8 qf[2][2];
    for (int mt = 0; mt < 2; mt++) {
        const unsigned short* qp = Qb + ((size_t)bh * SS + q0 + wi * 32 + mt * 16 + c) * 64;
        qf[mt][0] = *(const bf16x8*)(qp + q4 * 8);
        qf[mt][1] = *(const bf16x8*)(qp + 32 + q4 * 8);
    }
    bf16x8 ones;
    for (int i = 0; i < 8; i++) ones[i] = (short)0x3F80;   // bf16 1.0
    const floatx4 fzero = {};                 // shared zero C-operand

    // staging: per group, 4 waves x 2 issues cover 512 K-chunks + 512 V-chunks (16B)
    int cidx0 = wi * 128 + lane, cidx1 = cidx0 + 64;
    int row0 = cidx0 >> 3, cc0 = cidx0 & 7;
    int row1 = cidx1 >> 3, cc1 = cidx1 & 7;
    int fk0 = (row0 & 3) | ((row0 >> 1) & 4);
    int fk1 = (row1 & 3) | ((row1 >> 1) & 4);
    const unsigned short* ksrc0 = Kbase + (size_t)row0 * 64 + (cc0 ^ fk0) * 8;
    const unsigned short* ksrc1 = Kbase + (size_t)row1 * 64 + (cc1 ^ fk1) * 8;
    const unsigned short* vsrc0 = Vbase + (size_t)row0 * SS + wg * 1024 + (cc0 ^ (row0 & 7)) * 8;
    const unsigned short* vsrc1 = Vbase + (size_t)row1 * SS + wg * 1024 + (cc1 ^ (row1 & 7)) * 8;
    unsigned short* kdst0 = &KVs[0][wg][0][0] + wi * 1024;
    unsigned short* kdst1 = kdst0 + 512;
    unsigned short* vdst0 = &KVs[1][wg][0][0] + wi * 1024;
    unsigned short* vdst1 = vdst0 + 512;

    // prime buffer 0 (this group's first tile)
    gl_lds16(ksrc0, kdst0); gl_lds16(ksrc1, kdst1);
    gl_lds16(vsrc0, vdst0); gl_lds16(vsrc1, vdst1);

    int mask_j0 = (q0 + wi * 32) & ~63;      // absolute diag tile for these rows
    int mglob0 = q0 + wi * 32 + c;           // diag column for m-tile 0
    int mglob1 = mglob0 + 16;                // diag column for m-tile 1
    floatx4 oacc[2][4] = {};
    floatx4 osum[2] = {};                     // row sums via ones-column MFMA

    for (int jt = 0; jt < 16; jt++) {
        int buf = jt & 1;
        int j0 = wg * 1024 + jt * 64;        // absolute j of this tile
        __syncthreads();                     // drains last iter's prefetch
        if (jt + 1 < 16) {
            int jl = (jt + 1) * 64;          // group-local j offset
            gl_lds16(ksrc0 + (size_t)jl * 64, kdst0 + (buf ^ 1) * 4096);
            gl_lds16(ksrc1 + (size_t)jl * 64, kdst1 + (buf ^ 1) * 4096);
            gl_lds16(vsrc0 + jl, vdst0 + (buf ^ 1) * 4096);
            gl_lds16(vsrc1 + jl, vdst1 + (buf ^ 1) * 4096);
        }
        const unsigned short* Ksb = &KVs[0][wg][buf][0];
        const unsigned short* Vsb = &KVs[1][wg][buf][0];

        // ---- QK^T for BOTH g-parts first (sa held; no vf held) ----
        floatx4 sa[2][2][2];                  // [g][mt][inner]
        for (int g = 0; g < 2; g++) {
            bf16x8 kf[2][2];
            for (int inner = 0; inner < 2; inner++) {
                int row = g * 32 + ((c >> 2) << 3) + inner * 4 + (c & 3);
                kf[inner][0] = *(const bf16x8*)&Ksb[row * 64 + ((q4 ^ (c & 7)) * 8)];
                kf[inner][1] = *(const bf16x8*)&Ksb[row * 64 + (((4 + q4) ^ (c & 7)) * 8)];
            }
            __builtin_amdgcn_s_setprio(1);
            for (int mt = 0; mt < 2; mt++)
                for (int inner = 0; inner < 2; inner++) {
                    floatx4 t = MFMA16(kf[inner][0], qf[mt][0], fzero);
                    t = MFMA16(kf[inner][1], qf[mt][1], t);
                    sa[g][mt][inner] = t;
                }
            __builtin_amdgcn_s_setprio(0);
        }

        if (j0 == mask_j0) {                  // wave-uniform, 1/16 iterations
            for (int g = 0; g < 2; g++)
                for (int inner = 0; inner < 2; inner++)
                    for (int r = 0; r < 4; r++) {
                        int jg = j0 + g * 32 + q4 * 8 + inner * 4 + r;
                        if (jg == mglob0) sa[g][0][inner][r] = -1e30f;
                        if (jg == mglob1) sa[g][1][inner][r] = -1e30f;
                    }
        }

        // ---- exp2 -> packed P -> PV (+ ones-MFMA row sums), per g-part ----
        for (int g = 0; g < 2; g++) {
            bf16x8 vf[4];
            for (int dt = 0; dt < 4; dt++) {
                int vrow = dt * 16 + c;
                vf[dt] = *(const bf16x8*)&Vsb[vrow * 64 + (((g * 4 + q4) ^ (c & 7)) * 8)];
            }
            for (int mt = 0; mt < 2; mt++) {
                float e0 = fast_exp2(sa[g][mt][0][0]), e1 = fast_exp2(sa[g][mt][0][1]);
                float e2 = fast_exp2(sa[g][mt][0][2]), e3 = fast_exp2(sa[g][mt][0][3]);
                float e4 = fast_exp2(sa[g][mt][1][0]), e5 = fast_exp2(sa[g][mt][1][1]);
                float e6 = fast_exp2(sa[g][mt][1][2]), e7 = fast_exp2(sa[g][mt][1][3]);
                union { bf16x8 v; unsigned int u[4]; } P;
                P.u[0] = cvtpk(e0, e1); P.u[1] = cvtpk(e2, e3);
                P.u[2] = cvtpk(e4, e5); P.u[3] = cvtpk(e6, e7);
                __builtin_amdgcn_s_setprio(1);
                for (int dt = 0; dt < 4; dt++)
                    oacc[mt][dt] = MFMA16(P.v, vf[dt], oacc[mt][dt]);
                osum[mt] = MFMA16(P.v, ones, osum[mt]);
                __builtin_amdgcn_s_setprio(0);
            }
        }
    }

    // ---- merge the two j-halves (exact: plain sums), then group 0 stores ----
    __syncthreads();                          // all compute done; LDS reusable
    float* p = (float*)&KVs[0][0][0][0] + ((size_t)(wi * 64 + lane)) * 41;
    if (wg == 1) {
        for (int mt = 0; mt < 2; mt++)
            for (int dt = 0; dt < 4; dt++)
                for (int r = 0; r < 4; r++)
                    p[mt * 16 + dt * 4 + r] = oacc[mt][dt][r];
        for (int mt = 0; mt < 2; mt++)
            for (int r = 0; r < 4; r++)
                p[32 + mt * 4 + r] = osum[mt][r];
    }
    __syncthreads();
    if (wg == 0) {
        for (int mt = 0; mt < 2; mt++)
            for (int dt = 0; dt < 4; dt++)
                for (int r = 0; r < 4; r++)
                    oacc[mt][dt][r] += p[mt * 16 + dt * 4 + r];
        for (int mt = 0; mt < 2; mt++)
            for (int r = 0; r < 4; r++)
                osum[mt][r] += p[32 + mt * 4 + r];

        for (int mt = 0; mt < 2; mt++) {
            for (int r = 0; r < 4; r++) {
                float inv = 1.0f / osum[mt][r];
                int s = q0 + wi * 32 + mt * 16 + q4 * 4 + r;
                for (int dt = 0; dt < 4; dt++)
                    AO[((size_t)b * SS + s) * 512 + h * 64 + dt * 16 + c] =
                        f2bf(oacc[mt][dt][r] * inv);
            }
        }
    }
}

// ---------------- output GEMM: out[8192,512] = AO @ Wo_t^T + bias (fp32 out) ----------------
__global__ __launch_bounds__(256, 4) void k_gemm_out(
    const unsigned short* __restrict__ A,    // [8192][512] bf16
    const unsigned short* __restrict__ Bt,   // [512][512] bf16 (n-major)
    const float* __restrict__ bias,
    float* __restrict__ out) {
    __shared__ unsigned short As[64 * 64];    // 8 KB
    __shared__ unsigned short Bs[64 * 64];    // 8 KB
    const int K = 512;
    int m0 = blockIdx.x * 64, n0 = blockIdx.y * 64;
    int tid = threadIdx.x;
    int w = tid >> 6, lane = tid & 63;
    int c = lane & 15, q4 = lane >> 4;

    floatx4 acc[4] = {};

    for (int k0 = 0; k0 < K; k0 += 64) {
        __syncthreads();
        for (int i = 0; i < 2; i++) {
            int cidx = i * 256 + tid;             // 0..511 chunks (each of As, Bs)
            int row = cidx >> 3, cc = cidx & 7;
            int gcc = cc ^ (row & 7);
            gl_lds16(A + (size_t)(m0 + row) * K + k0 + gcc * 8,
                     As + (size_t)(i * 256 + w * 64) * 8);
            gl_lds16(Bt + (size_t)(n0 + row) * K + k0 + gcc * 8,
                     Bs + (size_t)(i * 256 + w * 64) * 8);
        }
        __syncthreads();
        for (int kh = 0; kh < 2; kh++) {
            int row = w * 16 + c;
            bf16x8 aF = *(const bf16x8*)&As[row * 64 + (((kh * 4 + q4) ^ (row & 7)) * 8)];
            bf16x8 bF[4];
            for (int nt = 0; nt < 4; nt++) {
                int rown = nt * 16 + c;
                bF[nt] = *(const bf16x8*)&Bs[rown * 64 + (((kh * 4 + q4) ^ (rown & 7)) * 8)];
            }
            for (int nt = 0; nt < 4; nt++)
                acc[nt] = MFMA16(aF, bF[nt], acc[nt]);
        }
    }

    for (int nt = 0; nt < 4; nt++) {
        int n = n0 + nt * 16 + c;
        float bv = bias[n];
        for (int r = 0; r < 4; r++) {
            int m = m0 + w * 16 + q4 * 4 + r;
            out[(size_t)m * 512 + n] = acc[nt][r] + bv;
        }
    }
}

extern "C" void kernel_launch(void* const* d_in, const int* in_sizes, int n_in,
                              void* d_out, int out_size, void* d_ws, size_t ws_size,
                              hipStream_t stream) {
    const float* x        = (const float*)d_in[0];
    const float* W_qkv    = (const float*)d_in[1];
    const float* log_temp = (const float*)d_in[2];
    const float* W_out    = (const float*)d_in[3];
    const float* b_out    = (const float*)d_in[4];
    float* out = (float*)d_out;

    char* ws = (char*)d_ws;
    unsigned short* Wq_t = (unsigned short*)(ws + 8388608);    //  1.5MB [1536][512]
    unsigned short* Wo_t = (unsigned short*)(ws + 9961472);    //  0.5MB [512][512]
    unsigned short* Qb   = (unsigned short*)(ws + 10485760);   //  8 MB  [32][2048][64]
    unsigned short* Kb   = (unsigned short*)(ws + 18874368);   //  8 MB  [32][2048][64]
    unsigned short* Vt   = (unsigned short*)(ws + 27262976);   //  8 MB  [32][64][2048]
    unsigned short* AO   = (unsigned short*)(ws + 35651584);   //  8 MB  [8192][512]

    k_prep<<<1024, 256, 0, stream>>>(W_qkv, W_out, Wq_t, Wo_t);
    k_gemm_qkv<<<dim3(64, 12), 256, 0, stream>>>(x, Wq_t, log_temp, Qb, Kb, Vt);
    k_attn<<<512, 512, 0, stream>>>(Qb, Kb, Vt, AO);
    k_gemm_out<<<dim3(128, 8), 256, 0, stream>>>(AO, Wo_t, b_out, out);
}